// Round 27
// baseline (219.935 us; speedup 1.0000x reference)
//
#include <hip/hip_runtime.h>
#include <math.h>

#define N_NODES 100000
#define N_EDGES 1600000
#define IN_DIM 500
#define HID 64
#define NCLS 16
#define KP 512     // padded K for layer-1 GEMM
#define NSTEPS 16  // KP/32
#define NBUK 391   // buckets of 256 dsts: bucket = dst >> 8
#define NPAD (NBUK * 256)
#define EPB_B 4096 // edges per bucket block (256 threads)
#define NBB ((N_EDGES + EPB_B - 1) / EPB_B)  // 391 bucket blocks
#define CAP 8192   // fixed slots per bucket (mean 4096; ws is ~800MB)
#define HP 72      // h row pitch (ushorts) in reused buf space

typedef __attribute__((ext_vector_type(8))) short short8;
typedef __attribute__((ext_vector_type(4))) float f32x4;

__device__ __forceinline__ unsigned short f2bf(float f) {
    unsigned u = __builtin_bit_cast(unsigned, f);
    return (unsigned short)((u + 0x7FFFu + ((u >> 16) & 1u)) >> 16);
}
__device__ __forceinline__ float bf2f(unsigned short s) {
    unsigned u = ((unsigned)s) << 16;
    return __builtin_bit_cast(float, u);
}
__device__ __forceinline__ unsigned pack2(unsigned short a, unsigned short b) {
    return (unsigned)a | ((unsigned)b << 16);
}
// async global->LDS, 16B per lane; LDS dest is wave-uniform base + lane*16
__device__ __forceinline__ void gload16(const void* g, void* l) {
    __builtin_amdgcn_global_load_lds(
        (const __attribute__((address_space(1))) unsigned*)g,
        (__attribute__((address_space(3))) unsigned*)l, 16, 0, 0);
}

// ---------------------------------------------------------------------------
// K0: build Bt[192][512] bf16 = transpose of {w1[0], w1[1], root1}, zero-pad
// K. Block 192 additionally initializes the bucket cursors.
// ---------------------------------------------------------------------------
__global__ __launch_bounds__(256) void k0_bt(
    const float* __restrict__ w1, const float* __restrict__ root1,
    unsigned short* __restrict__ Bt, int* __restrict__ bkcur)
{
    const int b = blockIdx.x;  // 0..192
    if (b == 192) {
        for (int i = threadIdx.x; i < NBUK; i += 256) bkcur[i] = i * CAP;
        return;
    }
    const float* src;
    int c;
    if (b < 64)        { src = w1;                c = b; }
    else if (b < 128)  { src = w1 + IN_DIM * HID; c = b - 64; }
    else               { src = root1;             c = b - 128; }
    for (int k = threadIdx.x; k < KP; k += 256) {
        float v = (k < IN_DIM) ? src[k * HID + c] : 0.f;
        Bt[b * KP + k] = f2bf(v);
    }
}

// ---------------------------------------------------------------------------
// FAT kernel with interleaved block mapping (R23-proven): every 5th block is
// a bucket block; the rest are k1 blocks.
// ---------------------------------------------------------------------------
union K1Smem {
    struct { float A[4][64 * 32]; unsigned short B[4][192 * 32]; } s;  // 80KB
    unsigned short O[64 * 264];       // k1 epilogue staging (33.8 KB)
    struct { int hcnt[NBUK]; int hbase[NBUK]; } bk;  // bucket body (3.1 KB)
};

__global__ __launch_bounds__(256) void fat_bucket_k1(
    const int* __restrict__ ei, const float* __restrict__ ea,
    int* __restrict__ bkcur, uint2* __restrict__ epk,
    const float* __restrict__ x, const unsigned short* __restrict__ Bt,
    unsigned short* __restrict__ xw01, float* __restrict__ aggH)
{
    __shared__ K1Smem sm;
    const int tid = threadIdx.x;
    const int bi = blockIdx.x;  // 0..1953

    if (bi % 5 == 0) {
        // ================= bucket-scatter body (id = bi/5, 0..390) =========
        const int start = (bi / 5) * EPB_B;
        const int eend = min(start + EPB_B, N_EDGES);

        for (int i = tid; i < NBUK; i += 256) sm.bk.hcnt[i] = 0;
        __syncthreads();

#pragma unroll
        for (int j = 0; j < EPB_B / 256; ++j) {
            const int e = start + j * 256 + tid;
            if (e < eend) atomicAdd(&sm.bk.hcnt[ei[N_EDGES + e] >> 8], 1);
        }
        __syncthreads();

        for (int b = tid; b < NBUK; b += 256) {
            const int c = sm.bk.hcnt[b];
            sm.bk.hbase[b] = c ? atomicAdd(&bkcur[b], c) : 0;
        }
        __syncthreads();
        for (int i = tid; i < NBUK; i += 256) sm.bk.hcnt[i] = 0;
        __syncthreads();

#pragma unroll
        for (int j = 0; j < EPB_B / 256; ++j) {
            const int e = start + j * 256 + tid;
            if (e < eend) {
                const int src = ei[e];
                const int dst = ei[N_EDGES + e];
                const float v = fminf(fmaxf(ea[e], 0.f), 1.f - 1e-6f);
                const unsigned vq = (unsigned)(v * 16777216.0f);  // 24-bit fixed
                const int bk = dst >> 8;
                const int r = atomicAdd(&sm.bk.hcnt[bk], 1);
                epk[sm.bk.hbase[bk] + r] =
                    make_uint2((unsigned)src, ((unsigned)(dst & 255) << 24) | vq);
            }
        }
        return;
    }

    // ================= k1 MFMA body (R16-proven; tile id = bi - (bi+4)/5) ==
    const int row0 = (bi - (bi + 4) / 5) * 64;
    const int w = tid >> 6;
    const int l = tid & 63;
    const int l16 = l & 15;
    const int koct = l >> 4;
    const int wr = w >> 1;
    const int wc = w & 1;

    f32x4 acc[2][6];
#pragma unroll
    for (int i = 0; i < 2; ++i)
#pragma unroll
        for (int j = 0; j < 6; ++j) acc[i][j] = (f32x4){0.f, 0.f, 0.f, 0.f};

    const int aChunk4 = (l & 7) * 4;
    const float* aBase[2];
    int aLdsOff[2];
#pragma unroll
    for (int i = 0; i < 2; ++i) {
        const int rowl = (2 * w + i) * 8 + (l >> 3);
        int grow = row0 + rowl;
        if (grow > N_NODES - 1) grow = N_NODES - 1;
        aBase[i] = x + (size_t)grow * IN_DIM;
        aLdsOff[i] = (2 * w + i) * 256;  // floats
    }
    const unsigned short* bBase[3];
    int bLdsOff[3];
#pragma unroll
    for (int i = 0; i < 3; ++i) {
        const int coll = (3 * w + i) * 16 + (l >> 2);
        bBase[i] = Bt + (size_t)coll * KP + (l & 3) * 8;
        bLdsOff[i] = (3 * w + i) * 512;  // ushorts
    }

    auto ISSUE = [&](int s) {
        const int k0 = s * 32;
        const int buf = s & 3;
#pragma unroll
        for (int i = 0; i < 2; ++i) {
            int gk = k0 + aChunk4; if (gk > IN_DIM - 4) gk = IN_DIM - 4;
            gload16(aBase[i] + gk, &sm.s.A[buf][aLdsOff[i]]);
        }
#pragma unroll
        for (int i = 0; i < 3; ++i)
            gload16(bBase[i] + k0, &sm.s.B[buf][bLdsOff[i]]);
    };

    ISSUE(0);
    ISSUE(1);
    ISSUE(2);

#pragma unroll
    for (int s = 0; s < NSTEPS; ++s) {
        if (s < NSTEPS - 2)       asm volatile("s_waitcnt vmcnt(10)" ::: "memory");
        else if (s == NSTEPS - 2) asm volatile("s_waitcnt vmcnt(5)" ::: "memory");
        else                      asm volatile("s_waitcnt vmcnt(0)" ::: "memory");
        __builtin_amdgcn_s_barrier();
        asm volatile("" ::: "memory");
        if (s + 3 < NSTEPS) ISSUE(s + 3);

        const int buf = s & 3;
        const float* LA = sm.s.A[buf];
        const unsigned short* LB = sm.s.B[buf];
        short8 af[2];
#pragma unroll
        for (int rb = 0; rb < 2; ++rb) {
            const int r = wr * 32 + rb * 16 + l16;
            f32x4 f0 = *(const f32x4*)&LA[r * 32 + koct * 8];
            f32x4 f1 = *(const f32x4*)&LA[r * 32 + koct * 8 + 4];
            short8 a;
            a[0] = (short)f2bf(f0[0]); a[1] = (short)f2bf(f0[1]);
            a[2] = (short)f2bf(f0[2]); a[3] = (short)f2bf(f0[3]);
            a[4] = (short)f2bf(f1[0]); a[5] = (short)f2bf(f1[1]);
            a[6] = (short)f2bf(f1[2]); a[7] = (short)f2bf(f1[3]);
            af[rb] = a;
        }
#pragma unroll
        for (int cf = 0; cf < 6; ++cf) {
            const int c = wc * 96 + cf * 16 + l16;
            short8 bfg = *(const short8*)&LB[c * 32 + koct * 8];
            acc[0][cf] = __builtin_amdgcn_mfma_f32_16x16x32_bf16(af[0], bfg, acc[0][cf], 0, 0, 0);
            acc[1][cf] = __builtin_amdgcn_mfma_f32_16x16x32_bf16(af[1], bfg, acc[1][cf], 0, 0, 0);
        }
    }
    __syncthreads();

#pragma unroll
    for (int rb = 0; rb < 2; ++rb)
#pragma unroll
        for (int cf = 0; cf < 6; ++cf) {
            const int cg = wc * 96 + cf * 16 + l16;
            if (96 * wc + cf * 16 < 128) {
#pragma unroll
                for (int reg = 0; reg < 4; ++reg) {
                    const int rloc = wr * 32 + rb * 16 + koct * 4 + reg;
                    const int idx = (cg < 64) ? (2 * cg) : (2 * cg - 127);
                    sm.O[rloc * 264 + idx] = f2bf(acc[rb][cf][reg]);
                }
            } else {
#pragma unroll
                for (int reg = 0; reg < 4; ++reg) {
                    const int r = row0 + wr * 32 + rb * 16 + koct * 4 + reg;
                    if (r < N_NODES) aggH[(size_t)r * HID + (cg - 128)] = acc[rb][cf][reg];
                }
            }
        }
    __syncthreads();
    {
        const int row = tid >> 2, q = tid & 3;
        const int rg = row0 + row;
        if (rg < N_NODES) {
#pragma unroll
            for (int j = 0; j < 4; ++j) {
                uint4 v = *(const uint4*)&sm.O[row * 264 + q * 32 + j * 8];
                *(uint4*)&xw01[(size_t)rg * 128 + q * 32 + j * 8] = v;
            }
        }
    }
}

// ---------------------------------------------------------------------------
// PLACE + AGG1 + K3 FUSED (R26-proven).
// ---------------------------------------------------------------------------
__global__ __launch_bounds__(1024) void place_agg1_k3(
    const int* __restrict__ bkcur, const uint2* __restrict__ epk,
    uint2* __restrict__ epkS, int* __restrict__ off, int* __restrict__ deg,
    const unsigned* __restrict__ xw01_u, const float* __restrict__ aggH,
    const float* __restrict__ b1, const float* __restrict__ w2,
    const float* __restrict__ root2, unsigned* __restrict__ hw01_u,
    float* __restrict__ agg2)
{
    __shared__ uint2 buf[CAP];               // 64 KB: records, then reused for h
    __shared__ unsigned short W2t[48 * HP];  // 6.9 KB
    __shared__ int hist[256];
    __shared__ int sc[256];
    __shared__ int cur[256];
    __shared__ int locs[256];
    __shared__ int degs[256];

    const int b = blockIdx.x;
    const int tid = threadIdx.x;
    const int start = b * CAP;
    const int cnt = bkcur[b] - start;

    // ---- stage W2t ----
    for (int i = tid; i < 48 * 64; i += 1024) {
        const int col = i >> 6, k = i & 63;
        float v;
        if (col < 16)      v = w2[k * NCLS + col];
        else if (col < 32) v = w2[HID * NCLS + k * NCLS + (col - 16)];
        else               v = root2[k * NCLS + (col - 32)];
        W2t[col * HP + k] = f2bf(v);
    }

    // ---- phase A: histogram ----
    if (tid < 256) hist[tid] = 0;
    __syncthreads();
    for (int i = tid; i < cnt; i += 1024)
        atomicAdd(&hist[epk[start + i].y >> 24], 1);
    __syncthreads();

    // scan: init, BARRIER, read->barrier->write->barrier
    int val = 0;
    if (tid < 256) { val = hist[tid]; sc[tid] = val; }
    __syncthreads();
    for (int d = 1; d < 256; d <<= 1) {
        int add = 0;
        if (tid < 256 && tid >= d) add = sc[tid - d];
        __syncthreads();
        if (tid < 256) sc[tid] += add;
        __syncthreads();
    }
    if (tid < 256) {
        const int myloc = sc[tid] - val;
        off[(b << 8) + tid] = start + myloc;
        deg[(b << 8) + tid] = val;
        locs[tid] = myloc;
        degs[tid] = val;
        cur[tid] = myloc;
    }
    __syncthreads();

    // rank-scatter into LDS
    for (int i = tid; i < cnt; i += 1024) {
        const uint2 u = epk[start + i];
        const int dl = u.y >> 24;
        const float v = (float)(u.y & 0xFFFFFFu) * 5.9604644775390625e-8f;
        const int pos = atomicAdd(&cur[dl], 1);
        buf[pos] = make_uint2(u.x, __builtin_bit_cast(unsigned, v));
    }
    __syncthreads();

    // coalesced stream-out for agg2's later use
    for (int i = tid; i < cnt; i += 1024)
        epkS[start + i] = buf[i];

    // ---- phase B: aggregate; accumulators in registers ----
    const int wv = tid >> 6;
    const int l = tid & 63;
    const float b1v = b1[l];
    float acct[16];
#pragma unroll
    for (int t = 0; t < 16; ++t) {
        const int nl = wv * 16 + t;
        const int n = (b << 8) + nl;
        float acc = 0.f;
        if (n < N_NODES) {
            const int lst = locs[nl];
            const int dgn = degs[nl];
            acc = aggH[(size_t)n * HID + l];
            for (int i = 0; i < dgn; i += 8) {
                unsigned srcs[8];
                float w0[8], w1v[8];
#pragma unroll
                for (int j = 0; j < 8; ++j) {
                    const bool ok = (i + j) < dgn;
                    const int idx = lst + (ok ? i + j : 0);
                    const uint2 u = buf[idx];
                    const float v = __builtin_bit_cast(float, u.y);
                    srcs[j] = u.x;
                    w0[j] = ok ? (1.f - v) : 0.f;
                    w1v[j] = ok ? v : 0.f;
                }
                unsigned g[8];
#pragma unroll
                for (int j = 0; j < 8; ++j) g[j] = xw01_u[(size_t)srcs[j] * 64 + l];
#pragma unroll
                for (int j = 0; j < 8; ++j) {
                    acc += w0[j] * bf2f((unsigned short)(g[j] & 0xFFFF));
                    acc += w1v[j] * bf2f((unsigned short)(g[j] >> 16));
                }
            }
        }
        acct[t] = acc;
    }
    __syncthreads();

    // ---- phase C: h -> bf16 LDS (reuse buf), 6 MFMAs per wave ----
    unsigned short* hb = (unsigned short*)buf;
#pragma unroll
    for (int t = 0; t < 16; ++t) {
        const int nl = wv * 16 + t;
        hb[nl * HP + l] = f2bf(fmaxf(acct[t] + b1v, 0.f));
    }
    __syncthreads();

    const int l16 = l & 15;
    const int koct = l >> 4;
    f32x4 c3[3];
#pragma unroll
    for (int j = 0; j < 3; ++j) c3[j] = (f32x4){0.f, 0.f, 0.f, 0.f};
#pragma unroll
    for (int s2 = 0; s2 < 2; ++s2) {
        short8 a = *(const short8*)&hb[(wv * 16 + l16) * HP + s2 * 32 + koct * 8];
#pragma unroll
        for (int cf = 0; cf < 3; ++cf) {
            short8 bf = *(const short8*)&W2t[(cf * 16 + l16) * HP + s2 * 32 + koct * 8];
            c3[cf] = __builtin_amdgcn_mfma_f32_16x16x32_bf16(a, bf, c3[cf], 0, 0, 0);
        }
    }
#pragma unroll
    for (int reg = 0; reg < 4; ++reg) {
        const int n = (b << 8) + wv * 16 + koct * 4 + reg;
        if (n < N_NODES) {
            hw01_u[(size_t)n * NCLS + l16] =
                pack2(f2bf(c3[0][reg]), f2bf(c3[1][reg]));
            agg2[(size_t)n * NCLS + l16] = c3[2][reg];
        }
    }
}

// ---------------------------------------------------------------------------
// AGG2 + log_softmax fused: 16 lanes per node, 16 nodes per block.
// 16 edges in flight (mean degree 16 -> mostly one latency round).
// ---------------------------------------------------------------------------
__global__ __launch_bounds__(256) void agg2_sm(
    const int* __restrict__ off, const int* __restrict__ deg,
    const uint2* __restrict__ epk, const unsigned* __restrict__ hw01_u,
    const float* __restrict__ agg2, const float* __restrict__ b2,
    float* __restrict__ out)
{
    const int n = blockIdx.x * 16 + (threadIdx.x >> 4);
    const int c = threadIdx.x & 15;
    const int start = off[n];
    const int dg = deg[n];

    float acc = agg2[(size_t)n * NCLS + c];
    for (int i = 0; i < dg; i += 16) {
        unsigned srcs[16];
        float w0[16], w1[16];
#pragma unroll
        for (int j = 0; j < 16; ++j) {
            const bool ok = (i + j) < dg;
            const int idx = ok ? (start + i + j) : start;
            const uint2 t = epk[idx];
            const float v = __builtin_bit_cast(float, t.y);
            srcs[j] = t.x;
            w0[j] = ok ? (1.f - v) : 0.f;
            w1[j] = ok ? v : 0.f;
        }
        unsigned g[16];
#pragma unroll
        for (int j = 0; j < 16; ++j) g[j] = hw01_u[(size_t)srcs[j] * NCLS + c];
#pragma unroll
        for (int j = 0; j < 16; ++j) {
            acc += w0[j] * bf2f((unsigned short)(g[j] & 0xFFFF));
            acc += w1[j] * bf2f((unsigned short)(g[j] >> 16));
        }
    }

    const float z = acc + b2[c];
    float m = z;
#pragma unroll
    for (int s = 1; s < 16; s <<= 1) m = fmaxf(m, __shfl_xor(m, s, 64));
    const float e = expf(z - m);
    float ssum = e;
#pragma unroll
    for (int s = 1; s < 16; s <<= 1) ssum += __shfl_xor(ssum, s, 64);
    out[(size_t)n * NCLS + c] = (z - m) - logf(ssum);
}

extern "C" void kernel_launch(void* const* d_in, const int* in_sizes, int n_in,
                              void* d_out, int out_size, void* d_ws, size_t ws_size,
                              hipStream_t stream) {
    const float* x = (const float*)d_in[0];
    const int* ei = (const int*)d_in[1];
    const float* ea = (const float*)d_in[2];
    const float* w1 = (const float*)d_in[3];
    const float* root1 = (const float*)d_in[4];
    const float* b1 = (const float*)d_in[5];
    const float* w2 = (const float*)d_in[6];
    const float* root2 = (const float*)d_in[7];
    const float* b2 = (const float*)d_in[8];
    float* out = (float*)d_out;

    char* ws = (char*)d_ws;
    unsigned short* xw01 = (unsigned short*)ws;                 // 25.6 MB
    float* aggH = (float*)(ws + 25600000);                      // 25.6 MB
    unsigned* hw01_u = (unsigned*)(ws + 51200000);              // 6.4 MB
    float* agg2 = (float*)(ws + 57600000);                      // 6.4 MB
    unsigned short* Bt = (unsigned short*)(ws + 64000000);      // 0.2 MB
    int* off = (int*)(ws + 64300000);                           // 0.4 MB (NPAD)
    int* deg = (int*)(ws + 64800000);                           // 0.4 MB (NPAD)
    int* bkcur = (int*)(ws + 65300000);                         // 1.6 KB
    uint2* epk = (uint2*)(ws + 65400000);                       // 25.6 MB (padded)
    uint2* epkS = (uint2*)(ws + 91100000);                      // 25.6 MB (padded)

    // k0 (builds Bt + inits bucket cursors)
    k0_bt<<<193, 256, 0, stream>>>(w1, root1, Bt, bkcur);

    // FAT: interleaved bucket (every 5th block) || k1 MFMA
    fat_bucket_k1<<<NBB + (N_NODES + 63) / 64, 256, 0, stream>>>(
        ei, ea, bkcur, epk, x, Bt, xw01, aggH);

    // fused place+agg1+k3 -> layer-2 agg+softmax
    place_agg1_k3<<<NBUK, 1024, 0, stream>>>(bkcur, epk, epkS, off, deg,
                                             (const unsigned*)xw01, aggH,
                                             b1, w2, root2, hw01_u, agg2);
    agg2_sm<<<N_NODES / 16, 256, 0, stream>>>(off, deg, epkS, hw01_u, agg2, b2, out);
}

// Round 28
// 213.529 us; speedup vs baseline: 1.0300x; 1.0300x over previous
//
#include <hip/hip_runtime.h>
#include <math.h>

#define N_NODES 100000
#define N_EDGES 1600000
#define IN_DIM 500
#define HID 64
#define NCLS 16
#define KP 512     // padded K for layer-1 GEMM
#define NSTEPS 16  // KP/32
#define NBUK 391   // buckets of 256 dsts: bucket = dst >> 8
#define NPAD (NBUK * 256)
#define EPB_B 4096 // edges per bucket block (256 threads)
#define NBB ((N_EDGES + EPB_B - 1) / EPB_B)  // 391 bucket blocks
#define CAP 8192   // fixed slots per bucket (mean 4096; ws is ~800MB)
#define HP 72      // h row pitch (ushorts) in reused buf space

typedef __attribute__((ext_vector_type(8))) short short8;
typedef __attribute__((ext_vector_type(4))) float f32x4;

__device__ __forceinline__ unsigned short f2bf(float f) {
    unsigned u = __builtin_bit_cast(unsigned, f);
    return (unsigned short)((u + 0x7FFFu + ((u >> 16) & 1u)) >> 16);
}
__device__ __forceinline__ float bf2f(unsigned short s) {
    unsigned u = ((unsigned)s) << 16;
    return __builtin_bit_cast(float, u);
}
__device__ __forceinline__ unsigned pack2(unsigned short a, unsigned short b) {
    return (unsigned)a | ((unsigned)b << 16);
}
// async global->LDS, 16B per lane; LDS dest is wave-uniform base + lane*16
__device__ __forceinline__ void gload16(const void* g, void* l) {
    __builtin_amdgcn_global_load_lds(
        (const __attribute__((address_space(1))) unsigned*)g,
        (__attribute__((address_space(3))) unsigned*)l, 16, 0, 0);
}

// ---------------------------------------------------------------------------
// K0: build Bt[192][512] bf16 = transpose of {w1[0], w1[1], root1}, zero-pad
// K. Block 192 additionally initializes the bucket cursors.
// ---------------------------------------------------------------------------
__global__ __launch_bounds__(256) void k0_bt(
    const float* __restrict__ w1, const float* __restrict__ root1,
    unsigned short* __restrict__ Bt, int* __restrict__ bkcur)
{
    const int b = blockIdx.x;  // 0..192
    if (b == 192) {
        for (int i = threadIdx.x; i < NBUK; i += 256) bkcur[i] = i * CAP;
        return;
    }
    const float* src;
    int c;
    if (b < 64)        { src = w1;                c = b; }
    else if (b < 128)  { src = w1 + IN_DIM * HID; c = b - 64; }
    else               { src = root1;             c = b - 128; }
    for (int k = threadIdx.x; k < KP; k += 256) {
        float v = (k < IN_DIM) ? src[k * HID + c] : 0.f;
        Bt[b * KP + k] = f2bf(v);
    }
}

// ---------------------------------------------------------------------------
// FAT kernel with interleaved block mapping (R23-proven): every 5th block is
// a bucket block; the rest are k1 blocks.
// ---------------------------------------------------------------------------
union K1Smem {
    struct { float A[4][64 * 32]; unsigned short B[4][192 * 32]; } s;  // 80KB
    unsigned short O[64 * 264];       // k1 epilogue staging (33.8 KB)
    struct { int hcnt[NBUK]; int hbase[NBUK]; } bk;  // bucket body (3.1 KB)
};

__global__ __launch_bounds__(256) void fat_bucket_k1(
    const int* __restrict__ ei, const float* __restrict__ ea,
    int* __restrict__ bkcur, uint2* __restrict__ epk,
    const float* __restrict__ x, const unsigned short* __restrict__ Bt,
    unsigned short* __restrict__ xw01, float* __restrict__ aggH)
{
    __shared__ K1Smem sm;
    const int tid = threadIdx.x;
    const int bi = blockIdx.x;  // 0..1953

    if (bi % 5 == 0) {
        // ================= bucket-scatter body (id = bi/5, 0..390) =========
        const int start = (bi / 5) * EPB_B;
        const int eend = min(start + EPB_B, N_EDGES);

        for (int i = tid; i < NBUK; i += 256) sm.bk.hcnt[i] = 0;
        __syncthreads();

#pragma unroll
        for (int j = 0; j < EPB_B / 256; ++j) {
            const int e = start + j * 256 + tid;
            if (e < eend) atomicAdd(&sm.bk.hcnt[ei[N_EDGES + e] >> 8], 1);
        }
        __syncthreads();

        for (int b = tid; b < NBUK; b += 256) {
            const int c = sm.bk.hcnt[b];
            sm.bk.hbase[b] = c ? atomicAdd(&bkcur[b], c) : 0;
        }
        __syncthreads();
        for (int i = tid; i < NBUK; i += 256) sm.bk.hcnt[i] = 0;
        __syncthreads();

#pragma unroll
        for (int j = 0; j < EPB_B / 256; ++j) {
            const int e = start + j * 256 + tid;
            if (e < eend) {
                const int src = ei[e];
                const int dst = ei[N_EDGES + e];
                const float v = fminf(fmaxf(ea[e], 0.f), 1.f - 1e-6f);
                const unsigned vq = (unsigned)(v * 16777216.0f);  // 24-bit fixed
                const int bk = dst >> 8;
                const int r = atomicAdd(&sm.bk.hcnt[bk], 1);
                epk[sm.bk.hbase[bk] + r] =
                    make_uint2((unsigned)src, ((unsigned)(dst & 255) << 24) | vq);
            }
        }
        return;
    }

    // ================= k1 MFMA body (R16-proven; tile id = bi - (bi+4)/5) ==
    const int row0 = (bi - (bi + 4) / 5) * 64;
    const int w = tid >> 6;
    const int l = tid & 63;
    const int l16 = l & 15;
    const int koct = l >> 4;
    const int wr = w >> 1;
    const int wc = w & 1;

    f32x4 acc[2][6];
#pragma unroll
    for (int i = 0; i < 2; ++i)
#pragma unroll
        for (int j = 0; j < 6; ++j) acc[i][j] = (f32x4){0.f, 0.f, 0.f, 0.f};

    const int aChunk4 = (l & 7) * 4;
    const float* aBase[2];
    int aLdsOff[2];
#pragma unroll
    for (int i = 0; i < 2; ++i) {
        const int rowl = (2 * w + i) * 8 + (l >> 3);
        int grow = row0 + rowl;
        if (grow > N_NODES - 1) grow = N_NODES - 1;
        aBase[i] = x + (size_t)grow * IN_DIM;
        aLdsOff[i] = (2 * w + i) * 256;  // floats
    }
    const unsigned short* bBase[3];
    int bLdsOff[3];
#pragma unroll
    for (int i = 0; i < 3; ++i) {
        const int coll = (3 * w + i) * 16 + (l >> 2);
        bBase[i] = Bt + (size_t)coll * KP + (l & 3) * 8;
        bLdsOff[i] = (3 * w + i) * 512;  // ushorts
    }

    auto ISSUE = [&](int s) {
        const int k0 = s * 32;
        const int buf = s & 3;
#pragma unroll
        for (int i = 0; i < 2; ++i) {
            int gk = k0 + aChunk4; if (gk > IN_DIM - 4) gk = IN_DIM - 4;
            gload16(aBase[i] + gk, &sm.s.A[buf][aLdsOff[i]]);
        }
#pragma unroll
        for (int i = 0; i < 3; ++i)
            gload16(bBase[i] + k0, &sm.s.B[buf][bLdsOff[i]]);
    };

    ISSUE(0);
    ISSUE(1);
    ISSUE(2);

#pragma unroll
    for (int s = 0; s < NSTEPS; ++s) {
        if (s < NSTEPS - 2)       asm volatile("s_waitcnt vmcnt(10)" ::: "memory");
        else if (s == NSTEPS - 2) asm volatile("s_waitcnt vmcnt(5)" ::: "memory");
        else                      asm volatile("s_waitcnt vmcnt(0)" ::: "memory");
        __builtin_amdgcn_s_barrier();
        asm volatile("" ::: "memory");
        if (s + 3 < NSTEPS) ISSUE(s + 3);

        const int buf = s & 3;
        const float* LA = sm.s.A[buf];
        const unsigned short* LB = sm.s.B[buf];
        short8 af[2];
#pragma unroll
        for (int rb = 0; rb < 2; ++rb) {
            const int r = wr * 32 + rb * 16 + l16;
            f32x4 f0 = *(const f32x4*)&LA[r * 32 + koct * 8];
            f32x4 f1 = *(const f32x4*)&LA[r * 32 + koct * 8 + 4];
            short8 a;
            a[0] = (short)f2bf(f0[0]); a[1] = (short)f2bf(f0[1]);
            a[2] = (short)f2bf(f0[2]); a[3] = (short)f2bf(f0[3]);
            a[4] = (short)f2bf(f1[0]); a[5] = (short)f2bf(f1[1]);
            a[6] = (short)f2bf(f1[2]); a[7] = (short)f2bf(f1[3]);
            af[rb] = a;
        }
#pragma unroll
        for (int cf = 0; cf < 6; ++cf) {
            const int c = wc * 96 + cf * 16 + l16;
            short8 bfg = *(const short8*)&LB[c * 32 + koct * 8];
            acc[0][cf] = __builtin_amdgcn_mfma_f32_16x16x32_bf16(af[0], bfg, acc[0][cf], 0, 0, 0);
            acc[1][cf] = __builtin_amdgcn_mfma_f32_16x16x32_bf16(af[1], bfg, acc[1][cf], 0, 0, 0);
        }
    }
    __syncthreads();

#pragma unroll
    for (int rb = 0; rb < 2; ++rb)
#pragma unroll
        for (int cf = 0; cf < 6; ++cf) {
            const int cg = wc * 96 + cf * 16 + l16;
            if (96 * wc + cf * 16 < 128) {
#pragma unroll
                for (int reg = 0; reg < 4; ++reg) {
                    const int rloc = wr * 32 + rb * 16 + koct * 4 + reg;
                    const int idx = (cg < 64) ? (2 * cg) : (2 * cg - 127);
                    sm.O[rloc * 264 + idx] = f2bf(acc[rb][cf][reg]);
                }
            } else {
#pragma unroll
                for (int reg = 0; reg < 4; ++reg) {
                    const int r = row0 + wr * 32 + rb * 16 + koct * 4 + reg;
                    if (r < N_NODES) aggH[(size_t)r * HID + (cg - 128)] = acc[rb][cf][reg];
                }
            }
        }
    __syncthreads();
    {
        const int row = tid >> 2, q = tid & 3;
        const int rg = row0 + row;
        if (rg < N_NODES) {
#pragma unroll
            for (int j = 0; j < 4; ++j) {
                uint4 v = *(const uint4*)&sm.O[row * 264 + q * 32 + j * 8];
                *(uint4*)&xw01[(size_t)rg * 128 + q * 32 + j * 8] = v;
            }
        }
    }
}

// ---------------------------------------------------------------------------
// PLACE + AGG1 + K3 FUSED (R26-proven).
// ---------------------------------------------------------------------------
__global__ __launch_bounds__(1024) void place_agg1_k3(
    const int* __restrict__ bkcur, const uint2* __restrict__ epk,
    uint2* __restrict__ epkS, int* __restrict__ off, int* __restrict__ deg,
    const unsigned* __restrict__ xw01_u, const float* __restrict__ aggH,
    const float* __restrict__ b1, const float* __restrict__ w2,
    const float* __restrict__ root2, unsigned* __restrict__ hw01_u,
    float* __restrict__ agg2)
{
    __shared__ uint2 buf[CAP];               // 64 KB: records, then reused for h
    __shared__ unsigned short W2t[48 * HP];  // 6.9 KB
    __shared__ int hist[256];
    __shared__ int sc[256];
    __shared__ int cur[256];
    __shared__ int locs[256];
    __shared__ int degs[256];

    const int b = blockIdx.x;
    const int tid = threadIdx.x;
    const int start = b * CAP;
    const int cnt = bkcur[b] - start;

    // ---- stage W2t ----
    for (int i = tid; i < 48 * 64; i += 1024) {
        const int col = i >> 6, k = i & 63;
        float v;
        if (col < 16)      v = w2[k * NCLS + col];
        else if (col < 32) v = w2[HID * NCLS + k * NCLS + (col - 16)];
        else               v = root2[k * NCLS + (col - 32)];
        W2t[col * HP + k] = f2bf(v);
    }

    // ---- phase A: histogram ----
    if (tid < 256) hist[tid] = 0;
    __syncthreads();
    for (int i = tid; i < cnt; i += 1024)
        atomicAdd(&hist[epk[start + i].y >> 24], 1);
    __syncthreads();

    // scan: init, BARRIER, read->barrier->write->barrier
    int val = 0;
    if (tid < 256) { val = hist[tid]; sc[tid] = val; }
    __syncthreads();
    for (int d = 1; d < 256; d <<= 1) {
        int add = 0;
        if (tid < 256 && tid >= d) add = sc[tid - d];
        __syncthreads();
        if (tid < 256) sc[tid] += add;
        __syncthreads();
    }
    if (tid < 256) {
        const int myloc = sc[tid] - val;
        off[(b << 8) + tid] = start + myloc;
        deg[(b << 8) + tid] = val;
        locs[tid] = myloc;
        degs[tid] = val;
        cur[tid] = myloc;
    }
    __syncthreads();

    // rank-scatter into LDS
    for (int i = tid; i < cnt; i += 1024) {
        const uint2 u = epk[start + i];
        const int dl = u.y >> 24;
        const float v = (float)(u.y & 0xFFFFFFu) * 5.9604644775390625e-8f;
        const int pos = atomicAdd(&cur[dl], 1);
        buf[pos] = make_uint2(u.x, __builtin_bit_cast(unsigned, v));
    }
    __syncthreads();

    // coalesced stream-out for agg2's later use
    for (int i = tid; i < cnt; i += 1024)
        epkS[start + i] = buf[i];

    // ---- phase B: aggregate; accumulators in registers ----
    const int wv = tid >> 6;
    const int l = tid & 63;
    const float b1v = b1[l];
    float acct[16];
#pragma unroll
    for (int t = 0; t < 16; ++t) {
        const int nl = wv * 16 + t;
        const int n = (b << 8) + nl;
        float acc = 0.f;
        if (n < N_NODES) {
            const int lst = locs[nl];
            const int dgn = degs[nl];
            acc = aggH[(size_t)n * HID + l];
            for (int i = 0; i < dgn; i += 8) {
                unsigned srcs[8];
                float w0[8], w1v[8];
#pragma unroll
                for (int j = 0; j < 8; ++j) {
                    const bool ok = (i + j) < dgn;
                    const int idx = lst + (ok ? i + j : 0);
                    const uint2 u = buf[idx];
                    const float v = __builtin_bit_cast(float, u.y);
                    srcs[j] = u.x;
                    w0[j] = ok ? (1.f - v) : 0.f;
                    w1v[j] = ok ? v : 0.f;
                }
                unsigned g[8];
#pragma unroll
                for (int j = 0; j < 8; ++j) g[j] = xw01_u[(size_t)srcs[j] * 64 + l];
#pragma unroll
                for (int j = 0; j < 8; ++j) {
                    acc += w0[j] * bf2f((unsigned short)(g[j] & 0xFFFF));
                    acc += w1v[j] * bf2f((unsigned short)(g[j] >> 16));
                }
            }
        }
        acct[t] = acc;
    }
    __syncthreads();

    // ---- phase C: h -> bf16 LDS (reuse buf), 6 MFMAs per wave ----
    unsigned short* hb = (unsigned short*)buf;
#pragma unroll
    for (int t = 0; t < 16; ++t) {
        const int nl = wv * 16 + t;
        hb[nl * HP + l] = f2bf(fmaxf(acct[t] + b1v, 0.f));
    }
    __syncthreads();

    const int l16 = l & 15;
    const int koct = l >> 4;
    f32x4 c3[3];
#pragma unroll
    for (int j = 0; j < 3; ++j) c3[j] = (f32x4){0.f, 0.f, 0.f, 0.f};
#pragma unroll
    for (int s2 = 0; s2 < 2; ++s2) {
        short8 a = *(const short8*)&hb[(wv * 16 + l16) * HP + s2 * 32 + koct * 8];
#pragma unroll
        for (int cf = 0; cf < 3; ++cf) {
            short8 bf = *(const short8*)&W2t[(cf * 16 + l16) * HP + s2 * 32 + koct * 8];
            c3[cf] = __builtin_amdgcn_mfma_f32_16x16x32_bf16(a, bf, c3[cf], 0, 0, 0);
        }
    }
#pragma unroll
    for (int reg = 0; reg < 4; ++reg) {
        const int n = (b << 8) + wv * 16 + koct * 4 + reg;
        if (n < N_NODES) {
            hw01_u[(size_t)n * NCLS + l16] =
                pack2(f2bf(c3[0][reg]), f2bf(c3[1][reg]));
            agg2[(size_t)n * NCLS + l16] = c3[2][reg];
        }
    }
}

// ---------------------------------------------------------------------------
// AGG2 + log_softmax fused: 16 lanes per node, 16 nodes per block.
// 8 edges in flight (R26-proven; ILP 16 regressed in R27).
// ---------------------------------------------------------------------------
__global__ __launch_bounds__(256) void agg2_sm(
    const int* __restrict__ off, const int* __restrict__ deg,
    const uint2* __restrict__ epk, const unsigned* __restrict__ hw01_u,
    const float* __restrict__ agg2, const float* __restrict__ b2,
    float* __restrict__ out)
{
    const int n = blockIdx.x * 16 + (threadIdx.x >> 4);
    const int c = threadIdx.x & 15;
    const int start = off[n];
    const int dg = deg[n];

    float acc = agg2[(size_t)n * NCLS + c];
    for (int i = 0; i < dg; i += 8) {
        unsigned srcs[8];
        float w0[8], w1[8];
#pragma unroll
        for (int j = 0; j < 8; ++j) {
            const bool ok = (i + j) < dg;
            const int idx = ok ? (start + i + j) : start;
            const uint2 t = epk[idx];
            const float v = __builtin_bit_cast(float, t.y);
            srcs[j] = t.x;
            w0[j] = ok ? (1.f - v) : 0.f;
            w1[j] = ok ? v : 0.f;
        }
        unsigned g[8];
#pragma unroll
        for (int j = 0; j < 8; ++j) g[j] = hw01_u[(size_t)srcs[j] * NCLS + c];
#pragma unroll
        for (int j = 0; j < 8; ++j) {
            acc += w0[j] * bf2f((unsigned short)(g[j] & 0xFFFF));
            acc += w1[j] * bf2f((unsigned short)(g[j] >> 16));
        }
    }

    const float z = acc + b2[c];
    float m = z;
#pragma unroll
    for (int s = 1; s < 16; s <<= 1) m = fmaxf(m, __shfl_xor(m, s, 64));
    const float e = expf(z - m);
    float ssum = e;
#pragma unroll
    for (int s = 1; s < 16; s <<= 1) ssum += __shfl_xor(ssum, s, 64);
    out[(size_t)n * NCLS + c] = (z - m) - logf(ssum);
}

extern "C" void kernel_launch(void* const* d_in, const int* in_sizes, int n_in,
                              void* d_out, int out_size, void* d_ws, size_t ws_size,
                              hipStream_t stream) {
    const float* x = (const float*)d_in[0];
    const int* ei = (const int*)d_in[1];
    const float* ea = (const float*)d_in[2];
    const float* w1 = (const float*)d_in[3];
    const float* root1 = (const float*)d_in[4];
    const float* b1 = (const float*)d_in[5];
    const float* w2 = (const float*)d_in[6];
    const float* root2 = (const float*)d_in[7];
    const float* b2 = (const float*)d_in[8];
    float* out = (float*)d_out;

    char* ws = (char*)d_ws;
    unsigned short* xw01 = (unsigned short*)ws;                 // 25.6 MB
    float* aggH = (float*)(ws + 25600000);                      // 25.6 MB
    unsigned* hw01_u = (unsigned*)(ws + 51200000);              // 6.4 MB
    float* agg2 = (float*)(ws + 57600000);                      // 6.4 MB
    unsigned short* Bt = (unsigned short*)(ws + 64000000);      // 0.2 MB
    int* off = (int*)(ws + 64300000);                           // 0.4 MB (NPAD)
    int* deg = (int*)(ws + 64800000);                           // 0.4 MB (NPAD)
    int* bkcur = (int*)(ws + 65300000);                         // 1.6 KB
    uint2* epk = (uint2*)(ws + 65400000);                       // 25.6 MB (padded)
    uint2* epkS = (uint2*)(ws + 91100000);                      // 25.6 MB (padded)

    // k0 (builds Bt + inits bucket cursors)
    k0_bt<<<193, 256, 0, stream>>>(w1, root1, Bt, bkcur);

    // FAT: interleaved bucket (every 5th block) || k1 MFMA
    fat_bucket_k1<<<NBB + (N_NODES + 63) / 64, 256, 0, stream>>>(
        ei, ea, bkcur, epk, x, Bt, xw01, aggH);

    // fused place+agg1+k3 -> layer-2 agg+softmax
    place_agg1_k3<<<NBUK, 1024, 0, stream>>>(bkcur, epk, epkS, off, deg,
                                             (const unsigned*)xw01, aggH,
                                             b1, w2, root2, hw01_u, agg2);
    agg2_sm<<<N_NODES / 16, 256, 0, stream>>>(off, deg, epkS, hw01_u, agg2, b2, out);
}